// Round 8
// baseline (39.875 us; speedup 1.0000x reference)
//
#include <hip/hip_runtime.h>

#define FD 32          // feature dim
#define RPB 16         // rows per block
#define CPT 4          // cols per thread -> block covers 1024 cols
#define BLK 256        // threads per block

// packed dual-fp32 add: vb holds (-b0,-b1), va holds (a0,a1) -> a-b for 2 d's, 1 inst
__device__ __forceinline__ float2 pk_add(float2 vb, float2 va) {
    float2 r;
    asm("v_pk_add_f32 %0, %1, %2" : "=v"(r) : "v"(vb), "v"(va));
    return r;
}
// acc = max(acc, |x|, |y|) in ONE inst (abs = free VOP3 input modifier)
__device__ __forceinline__ float max3abs(float a, float x, float y) {
    float r;
    asm("v_max3_f32 %0, %1, abs(%2), abs(%3)" : "=v"(r) : "v"(a), "v"(x), "v"(y));
    return r;
}
// Opaque re-definition: values become asm outputs -> the compiler cannot
// rematerialize (re-load) them inside the loop; they MUST stay in VGPRs.
// (Rounds 4/5/7 all lost B residency to remat/spill; this pins it.)
#define PIN8(a) asm volatile("" : "+v"(a[0]), "+v"(a[1]), "+v"(a[2]), "+v"(a[3]), \
                                  "+v"(a[4]), "+v"(a[5]), "+v"(a[6]), "+v"(a[7]))

// (256, 2): VGPR budget up to 256 so the 128-float B set + acc/addr fits w/o spill.
__global__ __launch_bounds__(256, 2) void cheb_kernel(
    const float* __restrict__ A, const float* __restrict__ B,
    float* __restrict__ C, int M)
{
    const int tid = threadIdx.x;
    const int c0  = blockIdx.x * (BLK * CPT) + tid * CPT;  // this thread's 4 cols
    const int r0  = blockIdx.y * RPB;

    // ---- Load this thread's 4 B columns, negated, into 128 pinned VGPRs.
    float2 b0[16], b1[16], b2[16], b3[16];
    {
        const float* brow = B + (size_t)c0 * FD;
#pragma unroll
        for (int q = 0; q < 8; ++q) {
            const float4 v0 = *reinterpret_cast<const float4*>(brow + q * 4);
            b0[2 * q + 0] = make_float2(-v0.x, -v0.y);
            b0[2 * q + 1] = make_float2(-v0.z, -v0.w);
            const float4 v1 = *reinterpret_cast<const float4*>(brow + FD + q * 4);
            b1[2 * q + 0] = make_float2(-v1.x, -v1.y);
            b1[2 * q + 1] = make_float2(-v1.z, -v1.w);
            const float4 v2 = *reinterpret_cast<const float4*>(brow + 2 * FD + q * 4);
            b2[2 * q + 0] = make_float2(-v2.x, -v2.y);
            b2[2 * q + 1] = make_float2(-v2.z, -v2.w);
            const float4 v3 = *reinterpret_cast<const float4*>(brow + 3 * FD + q * 4);
            b3[2 * q + 0] = make_float2(-v3.x, -v3.y);
            b3[2 * q + 1] = make_float2(-v3.z, -v3.w);
        }
    }
    PIN8(b0); PIN8((b0 + 8)); PIN8(b1); PIN8((b1 + 8));
    PIN8(b2); PIN8((b2 + 8)); PIN8(b3); PIN8((b3 + 8));

    // ---- Stream A rows: wave-uniform float4 loads (one 16B L1 transaction each,
    // broadcast to 64 lanes; software-pipelined across unrolled iterations).
#pragma unroll 2
    for (int r = 0; r < RPB; ++r) {
        const float* arow = A + (size_t)(r0 + r) * FD;
        float4 a[8];
#pragma unroll
        for (int q = 0; q < 8; ++q)
            a[q] = *reinterpret_cast<const float4*>(arow + q * 4);

        float acc0 = 0.0f, acc1 = 0.0f, acc2 = 0.0f, acc3 = 0.0f;
#pragma unroll
        for (int q = 0; q < 8; ++q) {
            const float2 alo = make_float2(a[q].x, a[q].y);
            const float2 ahi = make_float2(a[q].z, a[q].w);
            float2 d;
            d = pk_add(b0[2 * q + 0], alo); acc0 = max3abs(acc0, d.x, d.y);
            d = pk_add(b1[2 * q + 0], alo); acc1 = max3abs(acc1, d.x, d.y);
            d = pk_add(b2[2 * q + 0], alo); acc2 = max3abs(acc2, d.x, d.y);
            d = pk_add(b3[2 * q + 0], alo); acc3 = max3abs(acc3, d.x, d.y);
            d = pk_add(b0[2 * q + 1], ahi); acc0 = max3abs(acc0, d.x, d.y);
            d = pk_add(b1[2 * q + 1], ahi); acc1 = max3abs(acc1, d.x, d.y);
            d = pk_add(b2[2 * q + 1], ahi); acc2 = max3abs(acc2, d.x, d.y);
            d = pk_add(b3[2 * q + 1], ahi); acc3 = max3abs(acc3, d.x, d.y);
        }
        // coalesced: wave writes 1KB contiguous
        float4 o; o.x = acc0; o.y = acc1; o.z = acc2; o.w = acc3;
        *reinterpret_cast<float4*>(C + (size_t)(r0 + r) * M + c0) = o;
    }
}

extern "C" void kernel_launch(void* const* d_in, const int* in_sizes, int n_in,
                              void* d_out, int out_size, void* d_ws, size_t ws_size,
                              hipStream_t stream) {
    const float* A = (const float*)d_in[0];
    const float* B = (const float*)d_in[1];
    float* C = (float*)d_out;
    const int N = in_sizes[0] / FD;   // 4096
    const int M = in_sizes[1] / FD;   // 4096
    dim3 grid(M / (BLK * CPT), N / RPB);   // 4 x 256 = 1024 blocks
    cheb_kernel<<<grid, BLK, 0, stream>>>(A, B, C, M);
}